// Round 7
// baseline (2259.612 us; speedup 1.0000x reference)
//
#include <hip/hip_runtime.h>
#include <math.h>

#define B 64
#define T 128
#define D 256
#define H 256
#define G3 768     // 3*H
#define NTH 512    // 8 waves
#define RESROWS 128

// ---------------------------------------------------------------------------
// Kernel 1: MX[b,t,:] = inputs[b,t,:] @ kernel + bias[0]
// ---------------------------------------------------------------------------
__global__ __launch_bounds__(256) void mx_gemm_kernel(const float* __restrict__ x,
                                                      const float* __restrict__ K,
                                                      const float* __restrict__ bias,
                                                      float* __restrict__ MX) {
    __shared__ float xt[16][D];
    const int r0 = blockIdx.x * 16;
    const int tid = threadIdx.x;

    for (int idx = tid; idx < 16 * D; idx += 256) {
        xt[idx >> 8][idx & 255] = x[(size_t)(r0 + (idx >> 8)) * D + (idx & 255)];
    }
    __syncthreads();

    float acc0[16], acc1[16], acc2[16];
#pragma unroll
    for (int r = 0; r < 16; ++r) { acc0[r] = 0.f; acc1[r] = 0.f; acc2[r] = 0.f; }

    for (int d = 0; d < D; ++d) {
        float k0 = K[(size_t)d * G3 + tid];
        float k1 = K[(size_t)d * G3 + 256 + tid];
        float k2 = K[(size_t)d * G3 + 512 + tid];
#pragma unroll
        for (int r = 0; r < 16; ++r) {
            float xv = xt[r][d];
            acc0[r] += xv * k0;
            acc1[r] += xv * k1;
            acc2[r] += xv * k2;
        }
    }

    float b0 = bias[tid], b1 = bias[256 + tid], b2 = bias[512 + tid];
    for (int r = 0; r < 16; ++r) {
        size_t row = (size_t)(r0 + r) * G3;
        MX[row + tid]       = acc0[r] + b0;
        MX[row + 256 + tid] = acc1[r] + b1;
        MX[row + 512 + tid] = acc2[r] + b2;
    }
}

// ---------------------------------------------------------------------------
// Kernel 2: single-block-per-batch GRU recurrence, fp32 everywhere.
//   R rows 0..127 resident in VGPRs (192 regs/thread, asm-pinned);
//   R rows 128..255 streamed from L2 each step (4-row lookahead).
//   thread t: q = t>>7 (row group, wave-uniform), cols c6 = 6*(t&127)..+5.
// Per step: bar0 | S1 p1[8 strips] (float4 LDS hist2) | bar1 | S2 hp reduce
//   + MX prefetch (t<256) | bar2 | S4 mh partials (resident FMA + stream)
//   | bar3 | S5 gates + hist/out write; crow prefetch (t in [256,384)).
// ---------------------------------------------------------------------------
__global__ __launch_bounds__(NTH, 2) void rnn_kernel(const float* __restrict__ cond,
                                                     const float* __restrict__ R,
                                                     const float* __restrict__ bias,
                                                     const float* __restrict__ MX,
                                                     float* __restrict__ out) {
    const int b  = blockIdx.x;
    const int t  = threadIdx.x;
    const int u  = t & 255;          // unit for S2/S5
    const int u4 = 4 * (t & 63);     // S1 unit-quad base
    const int jq = t >> 6;           // 0..7  S1 j-strip (wave-uniform)
    const int q  = t >> 7;           // 0..3  S4 row group (wave-uniform)
    const int c6 = 6 * (t & 127);    // S4 col base (6 cols)

    __shared__ float hist2[T][H];                  // 131072 B (time-major)
    __shared__ __align__(16) float hpl[H];         //   1024 B
    __shared__ float p1[8][H];                     //   8192 B
    __shared__ float p2[4][G3];                    //  12288 B
    __shared__ float crow[2][T];                   //   1024 B  => 153600 B

    const float* condb = cond + (size_t)b * T * T;
    const float* mxb   = MX   + (size_t)b * T * G3;
    float*       outb  = out  + (size_t)b * T * H;

    // ---- one-time: resident R rows 32q..32q+31, cols c6..c6+5 (fp32, exact)
    float2 Ra[32], Rb[32], Rc[32];
    {
        const float* base = R + (size_t)(32 * q) * G3 + c6;
#pragma unroll
        for (int r = 0; r < 32; ++r) {
            Ra[r] = *reinterpret_cast<const float2*>(base + (size_t)r * G3);
            Rb[r] = *reinterpret_cast<const float2*>(base + (size_t)r * G3 + 2);
            Rc[r] = *reinterpret_cast<const float2*>(base + (size_t)r * G3 + 4);
        }
        // liveness pin: values become opaque -> compiler cannot rematerialize
#pragma unroll
        for (int r = 0; r < 32; ++r) {
            asm volatile("" : "+v"(Ra[r].x), "+v"(Ra[r].y),
                             "+v"(Rb[r].x), "+v"(Rb[r].y),
                             "+v"(Rc[r].x), "+v"(Rc[r].y));
        }
    }
    const float* Rstr = R + (size_t)(RESROWS + 32 * q) * G3 + c6;  // streamed base

    float b2z = 0.f, b2r = 0.f, b2h = 0.f;
    if (t < 256) {
        b2z = bias[G3 + u];
        b2r = bias[G3 + 256 + u];
        b2h = bias[G3 + 512 + u];
    }
    if (t >= 256 && t < 384) crow[1][t - 256] = condb[T + (t - 256)];

    // ---- step 0: h_prev = 0 -> mh = bias[1]
    float hp_reg = 0.f;
    if (t < 256) {
        const float xz = mxb[u], xr = mxb[256 + u], xh = mxb[512 + u];
        const float z    = 1.f / (1.f + expf(-(xz + b2z)));
        const float r    = 1.f / (1.f + expf(-(xr + b2r)));
        const float cand = tanhf(xh + r * b2h);
        const float hn   = (1.f - z) * cand;
        hist2[0][u] = hn;
        outb[u]     = hn;
    }

    for (int i = 1; i < T; ++i) {
        __syncthreads();                           // bar0: hist2[i-1], crow[i&1] ready

        // ---- S1: p1[jq][u4..u4+3] = sum over j-strip of c[i,j]*hist2[j][u4..]
        {
            const float* cr = crow[i & 1];
            const int len = (i + 7) >> 3;
            const int j0 = jq * len;
            const int j1 = min(i, j0 + len);
            float4 a = make_float4(0.f, 0.f, 0.f, 0.f);
            for (int j = j0; j < j1; ++j) {
                const float c = cr[j];
                const float4 hv = *reinterpret_cast<const float4*>(&hist2[j][u4]);
                a.x = fmaf(c, hv.x, a.x);
                a.y = fmaf(c, hv.y, a.y);
                a.z = fmaf(c, hv.z, a.z);
                a.w = fmaf(c, hv.w, a.w);
            }
            *reinterpret_cast<float4*>(&p1[jq][u4]) = a;
        }
        __syncthreads();                           // bar1

        // ---- S2: hp reduce + MX row prefetch (t<256)
        float xz = 0.f, xr = 0.f, xh = 0.f;
        if (t < 256) {
            const float* mrow = mxb + (size_t)i * G3;
            xz = mrow[u];
            xr = mrow[256 + u];
            xh = mrow[512 + u];
            float hp = p1[0][u];
#pragma unroll
            for (int s = 1; s < 8; ++s) hp += p1[s][u];
            hp_reg = hp;
            hpl[u] = hp;
        }
        __syncthreads();                           // bar2: hpl ready

        // ---- S4: mh partials: resident-register FMA + L2 stream (rows 128..255)
        {
            float a0 = 0.f, a1 = 0.f, a2 = 0.f, a3 = 0.f, a4 = 0.f, a5 = 0.f;
            // resident rows 32q..32q+31
            {
                const float4* hv4 = reinterpret_cast<const float4*>(&hpl[32 * q]);
#pragma unroll
                for (int r4 = 0; r4 < 8; ++r4) {
                    const float4 h4 = hv4[r4];
#define RESMAC(hv, rr)                                        \
                    a0 = fmaf((hv), Ra[rr].x, a0);            \
                    a1 = fmaf((hv), Ra[rr].y, a1);            \
                    a2 = fmaf((hv), Rb[rr].x, a2);            \
                    a3 = fmaf((hv), Rb[rr].y, a3);            \
                    a4 = fmaf((hv), Rc[rr].x, a4);            \
                    a5 = fmaf((hv), Rc[rr].y, a5);
                    RESMAC(h4.x, 4 * r4 + 0)
                    RESMAC(h4.y, 4 * r4 + 1)
                    RESMAC(h4.z, 4 * r4 + 2)
                    RESMAC(h4.w, 4 * r4 + 3)
#undef RESMAC
                }
            }
            // streamed rows 128+32q..+31, 4-row lookahead (static rotation)
            {
                const float* hs = &hpl[RESROWS + 32 * q];
                float2 bufa[4], bufb[4], bufc[4];
#pragma unroll
                for (int d0 = 0; d0 < 4; ++d0) {
                    bufa[d0] = *reinterpret_cast<const float2*>(Rstr + (size_t)d0 * G3);
                    bufb[d0] = *reinterpret_cast<const float2*>(Rstr + (size_t)d0 * G3 + 2);
                    bufc[d0] = *reinterpret_cast<const float2*>(Rstr + (size_t)d0 * G3 + 4);
                }
#pragma unroll
                for (int m = 0; m < 32; ++m) {
                    const int s = m & 3;
                    const float hv = hs[m];
                    const float2 wa = bufa[s], wb = bufb[s], wc = bufc[s];
                    if (m + 4 < 32) {
                        bufa[s] = *reinterpret_cast<const float2*>(Rstr + (size_t)(m + 4) * G3);
                        bufb[s] = *reinterpret_cast<const float2*>(Rstr + (size_t)(m + 4) * G3 + 2);
                        bufc[s] = *reinterpret_cast<const float2*>(Rstr + (size_t)(m + 4) * G3 + 4);
                    }
                    a0 = fmaf(hv, wa.x, a0);
                    a1 = fmaf(hv, wa.y, a1);
                    a2 = fmaf(hv, wb.x, a2);
                    a3 = fmaf(hv, wb.y, a3);
                    a4 = fmaf(hv, wc.x, a4);
                    a5 = fmaf(hv, wc.y, a5);
                }
            }
            *reinterpret_cast<float2*>(&p2[q][c6])     = make_float2(a0, a1);
            *reinterpret_cast<float2*>(&p2[q][c6 + 2]) = make_float2(a2, a3);
            *reinterpret_cast<float2*>(&p2[q][c6 + 4]) = make_float2(a4, a5);
        }
        __syncthreads();                           // bar3

        // ---- S5: gates (t<256); cond-row prefetch (t in [256,384))
        if (t < 256) {
            float mz = b2z, mr_ = b2r, mc = b2h;
#pragma unroll
            for (int s = 0; s < 4; ++s) {
                mz  += p2[s][u];
                mr_ += p2[s][256 + u];
                mc  += p2[s][512 + u];
            }
            const float z    = 1.f / (1.f + expf(-(xz + mz)));
            const float r    = 1.f / (1.f + expf(-(xr + mr_)));
            const float cand = tanhf(xh + r * mc);
            const float hn   = z * hp_reg + (1.f - z) * cand;
            hist2[i][u] = hn;
            outb[(size_t)i * H + u] = hn;
        } else if (t < 384 && i + 1 < T) {
            crow[(i + 1) & 1][t - 256] = condb[(size_t)(i + 1) * T + (t - 256)];
        }
    }
}

extern "C" void kernel_launch(void* const* d_in, const int* in_sizes, int n_in,
                              void* d_out, int out_size, void* d_ws, size_t ws_size,
                              hipStream_t stream) {
    const float* inputs     = (const float*)d_in[0];  // [B,T,D]
    const float* conditions = (const float*)d_in[1];  // [B,T,T]
    const float* kern       = (const float*)d_in[2];  // [D,3H]
    const float* rker       = (const float*)d_in[3];  // [H,3H]
    const float* bias       = (const float*)d_in[4];  // [2,3H]
    float* out = (float*)d_out;                       // [B,T,H]
    float* MX  = (float*)d_ws;                        // [B*T, 3H]

    mx_gemm_kernel<<<(B * T) / 16, 256, 0, stream>>>(inputs, kern, bias, MX);
    rnn_kernel<<<B, NTH, 0, stream>>>(conditions, rker, bias, MX, out);
}

// Round 8
// 2257.512 us; speedup vs baseline: 1.0009x; 1.0009x over previous
//
#include <hip/hip_runtime.h>
#include <math.h>

#define B 64
#define T 128
#define D 256
#define H 256
#define G3 768     // 3*H
#define NTH 512    // 8 waves
#define DR 28      // resident rows per row-group (VGPR): 4*28 = 112 rows of 256
#define NS 36      // streamed rows per row-group (L2): 4*36 = 144 rows

// ---------------------------------------------------------------------------
// Kernel 1: MX[b,t,:] = inputs[b,t,:] @ kernel + bias[0]
// ---------------------------------------------------------------------------
__global__ __launch_bounds__(256) void mx_gemm_kernel(const float* __restrict__ x,
                                                      const float* __restrict__ K,
                                                      const float* __restrict__ bias,
                                                      float* __restrict__ MX) {
    __shared__ float xt[16][D];
    const int r0 = blockIdx.x * 16;
    const int tid = threadIdx.x;

    for (int idx = tid; idx < 16 * D; idx += 256) {
        xt[idx >> 8][idx & 255] = x[(size_t)(r0 + (idx >> 8)) * D + (idx & 255)];
    }
    __syncthreads();

    float acc0[16], acc1[16], acc2[16];
#pragma unroll
    for (int r = 0; r < 16; ++r) { acc0[r] = 0.f; acc1[r] = 0.f; acc2[r] = 0.f; }

    for (int d = 0; d < D; ++d) {
        float k0 = K[(size_t)d * G3 + tid];
        float k1 = K[(size_t)d * G3 + 256 + tid];
        float k2 = K[(size_t)d * G3 + 512 + tid];
#pragma unroll
        for (int r = 0; r < 16; ++r) {
            float xv = xt[r][d];
            acc0[r] += xv * k0;
            acc1[r] += xv * k1;
            acc2[r] += xv * k2;
        }
    }

    float b0 = bias[tid], b1 = bias[256 + tid], b2 = bias[512 + tid];
    for (int r = 0; r < 16; ++r) {
        size_t row = (size_t)(r0 + r) * G3;
        MX[row + tid]       = acc0[r] + b0;
        MX[row + 256 + tid] = acc1[r] + b1;
        MX[row + 512 + tid] = acc2[r] + b2;
    }
}

// ---------------------------------------------------------------------------
// Kernel 2: single-block-per-batch GRU recurrence, fp32 everywhere.
//   Occupancy pinned to 2 waves/EU (amdgpu_waves_per_eu(2,2)) -> 256-VGPR
//   budget, so the per-thread resident R slice (168 floats, pinned once after
//   load) truly lives in VGPRs. Rows 64q..64q+27 resident; rows 64q+28..64q+63
//   streamed from L2 per step with 4-row lookahead.
//   thread t: q = t>>7 (row group, wave-uniform), cols c6 = 6*(t&127)..+5.
// ---------------------------------------------------------------------------
__global__ __attribute__((amdgpu_waves_per_eu(2, 2))) __launch_bounds__(NTH)
void rnn_kernel(const float* __restrict__ cond,
                const float* __restrict__ R,
                const float* __restrict__ bias,
                const float* __restrict__ MX,
                float* __restrict__ out) {
    const int b  = blockIdx.x;
    const int t  = threadIdx.x;
    const int u  = t & 255;          // unit for S2/S5
    const int u4 = 4 * (t & 63);     // S1 unit-quad base
    const int jq = t >> 6;           // 0..7  S1 j-strip (wave-uniform)
    const int q  = t >> 7;           // 0..3  S4 row group (wave-uniform)
    const int c6 = 6 * (t & 127);    // S4 col base (6 cols)

    __shared__ float hist2[T][H];                  // 131072 B (time-major)
    __shared__ __align__(16) float hpl[H];         //   1024 B
    __shared__ float p1[8][H];                     //   8192 B
    __shared__ float p2[4][G3];                    //  12288 B
    __shared__ float crow[2][T];                   //   1024 B  => 153600 B

    const float* condb = cond + (size_t)b * T * T;
    const float* mxb   = MX   + (size_t)b * T * G3;
    float*       outb  = out  + (size_t)b * T * H;

    // ---- one-time: resident R rows 64q..64q+DR-1, cols c6..c6+5 (fp32)
    float2 Ra[DR], Rb[DR], Rc[DR];
    {
        const float* base = R + (size_t)(64 * q) * G3 + c6;
#pragma unroll
        for (int r = 0; r < DR; ++r) {
            Ra[r] = *reinterpret_cast<const float2*>(base + (size_t)r * G3);
            Rb[r] = *reinterpret_cast<const float2*>(base + (size_t)r * G3 + 2);
            Rc[r] = *reinterpret_cast<const float2*>(base + (size_t)r * G3 + 4);
        }
        // liveness pin: forbids rematerialization; with the 256-reg budget and
        // ~225 peak pressure the allocator keeps these resident (no spill).
#pragma unroll
        for (int r = 0; r < DR; ++r) {
            asm volatile("" : "+v"(Ra[r].x), "+v"(Ra[r].y),
                             "+v"(Rb[r].x), "+v"(Rb[r].y),
                             "+v"(Rc[r].x), "+v"(Rc[r].y));
        }
    }
    const float* Rstr = R + (size_t)(64 * q + DR) * G3 + c6;  // streamed base

    float b2z = 0.f, b2r = 0.f, b2h = 0.f;
    if (t < 256) {
        b2z = bias[G3 + u];
        b2r = bias[G3 + 256 + u];
        b2h = bias[G3 + 512 + u];
    }
    if (t >= 256 && t < 384) crow[1][t - 256] = condb[T + (t - 256)];

    // ---- step 0: h_prev = 0 -> mh = bias[1]
    float hp_reg = 0.f;
    if (t < 256) {
        const float xz = mxb[u], xr = mxb[256 + u], xh = mxb[512 + u];
        const float z    = 1.f / (1.f + expf(-(xz + b2z)));
        const float r    = 1.f / (1.f + expf(-(xr + b2r)));
        const float cand = tanhf(xh + r * b2h);
        const float hn   = (1.f - z) * cand;
        hist2[0][u] = hn;
        outb[u]     = hn;
    }

    for (int i = 1; i < T; ++i) {
        __syncthreads();                           // bar0: hist2[i-1], crow[i&1] ready

        // ---- S1: p1[jq][u4..u4+3] = sum over j-strip of c[i,j]*hist2[j][u4..]
        {
            const float* cr = crow[i & 1];
            const int len = (i + 7) >> 3;
            const int j0 = jq * len;
            const int j1 = min(i, j0 + len);
            float4 a = make_float4(0.f, 0.f, 0.f, 0.f);
            for (int j = j0; j < j1; ++j) {
                const float c = cr[j];
                const float4 hv = *reinterpret_cast<const float4*>(&hist2[j][u4]);
                a.x = fmaf(c, hv.x, a.x);
                a.y = fmaf(c, hv.y, a.y);
                a.z = fmaf(c, hv.z, a.z);
                a.w = fmaf(c, hv.w, a.w);
            }
            *reinterpret_cast<float4*>(&p1[jq][u4]) = a;
        }
        __syncthreads();                           // bar1

        // ---- S2: hp reduce + MX row prefetch (t<256)
        float xz = 0.f, xr = 0.f, xh = 0.f;
        if (t < 256) {
            const float* mrow = mxb + (size_t)i * G3;
            xz = mrow[u];
            xr = mrow[256 + u];
            xh = mrow[512 + u];
            float hp = p1[0][u];
#pragma unroll
            for (int s = 1; s < 8; ++s) hp += p1[s][u];
            hp_reg = hp;
            hpl[u] = hp;
        }
        __syncthreads();                           // bar2: hpl ready

        // ---- S4: mh partials: resident-register FMA + L2 stream
        {
            float a0 = 0.f, a1 = 0.f, a2 = 0.f, a3 = 0.f, a4 = 0.f, a5 = 0.f;
            // resident rows 64q..64q+DR-1
            {
                const float4* hv4 = reinterpret_cast<const float4*>(&hpl[64 * q]);
#pragma unroll
                for (int r4 = 0; r4 < DR / 4; ++r4) {
                    const float4 h4 = hv4[r4];
#define RESMAC(hv, rr)                                        \
                    a0 = fmaf((hv), Ra[rr].x, a0);            \
                    a1 = fmaf((hv), Ra[rr].y, a1);            \
                    a2 = fmaf((hv), Rb[rr].x, a2);            \
                    a3 = fmaf((hv), Rb[rr].y, a3);            \
                    a4 = fmaf((hv), Rc[rr].x, a4);            \
                    a5 = fmaf((hv), Rc[rr].y, a5);
                    RESMAC(h4.x, 4 * r4 + 0)
                    RESMAC(h4.y, 4 * r4 + 1)
                    RESMAC(h4.z, 4 * r4 + 2)
                    RESMAC(h4.w, 4 * r4 + 3)
#undef RESMAC
                }
            }
            // streamed rows 64q+DR .. 64q+63, 4-row lookahead (static rotation)
            {
                const float* hs = &hpl[64 * q + DR];
                float2 bufa[4], bufb[4], bufc[4];
#pragma unroll
                for (int d0 = 0; d0 < 4; ++d0) {
                    bufa[d0] = *reinterpret_cast<const float2*>(Rstr + (size_t)d0 * G3);
                    bufb[d0] = *reinterpret_cast<const float2*>(Rstr + (size_t)d0 * G3 + 2);
                    bufc[d0] = *reinterpret_cast<const float2*>(Rstr + (size_t)d0 * G3 + 4);
                }
#pragma unroll
                for (int m = 0; m < NS; ++m) {
                    const int s = m & 3;
                    const float hv = hs[m];
                    const float2 wa = bufa[s], wb = bufb[s], wc = bufc[s];
                    if (m + 4 < NS) {
                        bufa[s] = *reinterpret_cast<const float2*>(Rstr + (size_t)(m + 4) * G3);
                        bufb[s] = *reinterpret_cast<const float2*>(Rstr + (size_t)(m + 4) * G3 + 2);
                        bufc[s] = *reinterpret_cast<const float2*>(Rstr + (size_t)(m + 4) * G3 + 4);
                    }
                    a0 = fmaf(hv, wa.x, a0);
                    a1 = fmaf(hv, wa.y, a1);
                    a2 = fmaf(hv, wb.x, a2);
                    a3 = fmaf(hv, wb.y, a3);
                    a4 = fmaf(hv, wc.x, a4);
                    a5 = fmaf(hv, wc.y, a5);
                }
            }
            *reinterpret_cast<float2*>(&p2[q][c6])     = make_float2(a0, a1);
            *reinterpret_cast<float2*>(&p2[q][c6 + 2]) = make_float2(a2, a3);
            *reinterpret_cast<float2*>(&p2[q][c6 + 4]) = make_float2(a4, a5);
        }
        __syncthreads();                           // bar3

        // ---- S5: gates (t<256); cond-row prefetch (t in [256,384))
        if (t < 256) {
            float mz = b2z, mr_ = b2r, mc = b2h;
#pragma unroll
            for (int s = 0; s < 4; ++s) {
                mz  += p2[s][u];
                mr_ += p2[s][256 + u];
                mc  += p2[s][512 + u];
            }
            const float z    = 1.f / (1.f + expf(-(xz + mz)));
            const float r    = 1.f / (1.f + expf(-(xr + mr_)));
            const float cand = tanhf(xh + r * mc);
            const float hn   = z * hp_reg + (1.f - z) * cand;
            hist2[i][u] = hn;
            outb[(size_t)i * H + u] = hn;
        } else if (t < 384 && i + 1 < T) {
            crow[(i + 1) & 1][t - 256] = condb[(size_t)(i + 1) * T + (t - 256)];
        }
    }
}

extern "C" void kernel_launch(void* const* d_in, const int* in_sizes, int n_in,
                              void* d_out, int out_size, void* d_ws, size_t ws_size,
                              hipStream_t stream) {
    const float* inputs     = (const float*)d_in[0];  // [B,T,D]
    const float* conditions = (const float*)d_in[1];  // [B,T,T]
    const float* kern       = (const float*)d_in[2];  // [D,3H]
    const float* rker       = (const float*)d_in[3];  // [H,3H]
    const float* bias       = (const float*)d_in[4];  // [2,3H]
    float* out = (float*)d_out;                       // [B,T,H]
    float* MX  = (float*)d_ws;                        // [B*T, 3H]

    mx_gemm_kernel<<<(B * T) / 16, 256, 0, stream>>>(inputs, kern, bias, MX);
    rnn_kernel<<<B, NTH, 0, stream>>>(conditions, rker, bias, MX, out);
}

// Round 9
// 2255.425 us; speedup vs baseline: 1.0019x; 1.0009x over previous
//
#include <hip/hip_runtime.h>
#include <math.h>

#define B 64
#define T 128
#define D 256
#define H 256
#define G3 768     // 3*H
#define NTH 1024   // 16 waves -> 1 block/CU, VGPR cap 128 (grantable)
#define RREG 8     // register-resident rows per row-group (8 groups x 8 = 64 rows)
#define RLDS 4     // LDS-resident rows per row-group     (8 groups x 4 = 32 rows)
#define RSTR 20    // streamed rows per row-group         (8 groups x 20 = 160 rows)

// ---------------------------------------------------------------------------
// Kernel 1: MX[b,t,:] = inputs[b,t,:] @ kernel + bias[0]
// ---------------------------------------------------------------------------
__global__ __launch_bounds__(256) void mx_gemm_kernel(const float* __restrict__ x,
                                                      const float* __restrict__ K,
                                                      const float* __restrict__ bias,
                                                      float* __restrict__ MX) {
    __shared__ float xt[16][D];
    const int r0 = blockIdx.x * 16;
    const int tid = threadIdx.x;

    for (int idx = tid; idx < 16 * D; idx += 256) {
        xt[idx >> 8][idx & 255] = x[(size_t)(r0 + (idx >> 8)) * D + (idx & 255)];
    }
    __syncthreads();

    float acc0[16], acc1[16], acc2[16];
#pragma unroll
    for (int r = 0; r < 16; ++r) { acc0[r] = 0.f; acc1[r] = 0.f; acc2[r] = 0.f; }

    for (int d = 0; d < D; ++d) {
        float k0 = K[(size_t)d * G3 + tid];
        float k1 = K[(size_t)d * G3 + 256 + tid];
        float k2 = K[(size_t)d * G3 + 512 + tid];
#pragma unroll
        for (int r = 0; r < 16; ++r) {
            float xv = xt[r][d];
            acc0[r] += xv * k0;
            acc1[r] += xv * k1;
            acc2[r] += xv * k2;
        }
    }

    float b0 = bias[tid], b1 = bias[256 + tid], b2 = bias[512 + tid];
    for (int r = 0; r < 16; ++r) {
        size_t row = (size_t)(r0 + r) * G3;
        MX[row + tid]       = acc0[r] + b0;
        MX[row + 256 + tid] = acc1[r] + b1;
        MX[row + 512 + tid] = acc2[r] + b2;
    }
}

// ---------------------------------------------------------------------------
// Kernel 2: single-block-per-batch GRU recurrence, fp32 everywhere.
//   R partition per row-group q (t>>7, rows 32q..32q+31), cols c6=6*(t&127):
//     rows 32q..32q+7    -> 48 floats/thread in VGPRs (fits the 128-reg cap)
//     rows 32q+8..32q+11 -> LDS (96 KB)
//     rows 32q+12..32q+31-> streamed from L2 each step (491 KB/step)
//   History lives in d_out itself (out[b,j,:] == h_j); rows are 1KB-aligned so
//   no cache line ever mixes written/unwritten data.
// Per step: bar0 | S1 p1[16 strips] (hist float4 from global x crow LDS)
//   | bar1 | S2 (t<256) hp reduce + MX prefetch | bar2 | S4 mh partials
//   (reg + LDS + stream) -> p2[8][G3] | bar3 | S5 (t<256) gates -> out;
//   (t in [256,384)) crow prefetch.
// ---------------------------------------------------------------------------
__global__ __launch_bounds__(NTH) void rnn_kernel(const float* __restrict__ cond,
                                                  const float* __restrict__ R,
                                                  const float* __restrict__ bias,
                                                  const float* __restrict__ MX,
                                                  float* out) {
    const int b  = blockIdx.x;
    const int t  = threadIdx.x;
    const int u  = t & 255;          // S2/S5 unit
    const int u4 = 4 * (t & 63);     // S1 unit-quad base
    const int jq = t >> 6;           // 0..15 S1 j-strip (wave-uniform)
    const int q  = t >> 7;           // 0..7  S4 row group (wave-uniform)
    const int c6 = 6 * (t & 127);    // S4 col base (6 cols)

    __shared__ float Rl[8 * RLDS * G3];            // 98304 B
    __shared__ float p1[16][H];                    // 16384 B
    __shared__ float p2[8][G3];                    // 24576 B
    __shared__ __align__(16) float hpl[H];         //  1024 B
    __shared__ float crow[2][T];                   //  1024 B  => 141312 B

    const float* condb = cond + (size_t)b * T * T;
    const float* mxb   = MX   + (size_t)b * T * G3;
    float*       outb  = out  + (size_t)b * T * H;

    // ---- one-time: LDS R rows (32q'+8 .. 32q'+11 for each group), coalesced
    for (int idx = t; idx < 8 * RLDS * G3; idx += NTH) {
        const int col = idx % G3;
        const int qr  = idx / G3;          // 0..31
        const int qq  = qr >> 2, rl = qr & 3;
        Rl[idx] = R[(size_t)(32 * qq + RREG + rl) * G3 + col];
    }

    // ---- one-time: register R rows 32q..32q+7, cols c6..c6+5 (48 floats)
    float2 Ra[RREG], Rb2[RREG], Rc[RREG];
    {
        const float* base = R + (size_t)(32 * q) * G3 + c6;
#pragma unroll
        for (int r = 0; r < RREG; ++r) {
            Ra[r]  = *reinterpret_cast<const float2*>(base + (size_t)r * G3);
            Rb2[r] = *reinterpret_cast<const float2*>(base + (size_t)r * G3 + 2);
            Rc[r]  = *reinterpret_cast<const float2*>(base + (size_t)r * G3 + 4);
        }
#pragma unroll
        for (int r = 0; r < RREG; ++r) {
            asm volatile("" : "+v"(Ra[r].x),  "+v"(Ra[r].y),
                             "+v"(Rb2[r].x), "+v"(Rb2[r].y),
                             "+v"(Rc[r].x),  "+v"(Rc[r].y));
        }
    }
    const float* Rstr = R + (size_t)(32 * q + RREG + RLDS) * G3 + c6;

    float b2z = 0.f, b2r = 0.f, b2h = 0.f;
    if (t < 256) {
        b2z = bias[G3 + u];
        b2r = bias[G3 + 256 + u];
        b2h = bias[G3 + 512 + u];
    }
    if (t >= 256 && t < 384) crow[1][t - 256] = condb[T + (t - 256)];

    // ---- step 0: h_prev = 0 -> mh = bias[1]
    float hp_reg = 0.f;
    if (t < 256) {
        const float xz = mxb[u], xr = mxb[256 + u], xh = mxb[512 + u];
        const float z    = 1.f / (1.f + expf(-(xz + b2z)));
        const float r    = 1.f / (1.f + expf(-(xr + b2r)));
        const float cand = tanhf(xh + r * b2h);
        outb[u] = (1.f - z) * cand;
    }

    for (int i = 1; i < T; ++i) {
        __syncthreads();                           // bar0: out row i-1, crow, Rl ready

        // ---- S1: p1[jq][u4..u4+3] = sum over j-strip of c[i,j]*h_j[u4..]
        {
            const float* cr = crow[i & 1];
            const int len = (i + 15) >> 4;
            const int j0 = jq * len;
            const int j1 = min(i, j0 + len);
            float4 a = make_float4(0.f, 0.f, 0.f, 0.f);
            for (int j = j0; j < j1; ++j) {
                const float c = cr[j];
                const float4 hv = *reinterpret_cast<const float4*>(&outb[(size_t)j * H + u4]);
                a.x = fmaf(c, hv.x, a.x);
                a.y = fmaf(c, hv.y, a.y);
                a.z = fmaf(c, hv.z, a.z);
                a.w = fmaf(c, hv.w, a.w);
            }
            *reinterpret_cast<float4*>(&p1[jq][u4]) = a;
        }
        __syncthreads();                           // bar1

        // ---- S2: hp reduce + MX row prefetch (t<256)
        float xz = 0.f, xr = 0.f, xh = 0.f;
        if (t < 256) {
            const float* mrow = mxb + (size_t)i * G3;
            xz = mrow[u];
            xr = mrow[256 + u];
            xh = mrow[512 + u];
            float hp = p1[0][u];
#pragma unroll
            for (int s = 1; s < 16; ++s) hp += p1[s][u];
            hp_reg = hp;
            hpl[u] = hp;
        }
        __syncthreads();                           // bar2: hpl ready

        // ---- S4: mh partials: reg rows + LDS rows + streamed rows
        {
            float a0 = 0.f, a1 = 0.f, a2 = 0.f, a3 = 0.f, a4 = 0.f, a5 = 0.f;
            // register rows 32q .. 32q+7
            {
                const float4* hv4 = reinterpret_cast<const float4*>(&hpl[32 * q]);
                const float4 h0 = hv4[0], h1 = hv4[1];
#define RESMAC(hv, rr)                                        \
                a0 = fmaf((hv), Ra[rr].x,  a0);               \
                a1 = fmaf((hv), Ra[rr].y,  a1);               \
                a2 = fmaf((hv), Rb2[rr].x, a2);               \
                a3 = fmaf((hv), Rb2[rr].y, a3);               \
                a4 = fmaf((hv), Rc[rr].x,  a4);               \
                a5 = fmaf((hv), Rc[rr].y,  a5);
                RESMAC(h0.x, 0) RESMAC(h0.y, 1) RESMAC(h0.z, 2) RESMAC(h0.w, 3)
                RESMAC(h1.x, 4) RESMAC(h1.y, 5) RESMAC(h1.z, 6) RESMAC(h1.w, 7)
#undef RESMAC
            }
            // LDS rows 32q+8 .. 32q+11
            {
#pragma unroll
                for (int rl = 0; rl < RLDS; ++rl) {
                    const float hv = hpl[32 * q + RREG + rl];
                    const float* w = &Rl[(q * RLDS + rl) * G3 + c6];
                    const float2 w0 = *reinterpret_cast<const float2*>(w);
                    const float2 w1 = *reinterpret_cast<const float2*>(w + 2);
                    const float2 w2 = *reinterpret_cast<const float2*>(w + 4);
                    a0 = fmaf(hv, w0.x, a0);
                    a1 = fmaf(hv, w0.y, a1);
                    a2 = fmaf(hv, w1.x, a2);
                    a3 = fmaf(hv, w1.y, a3);
                    a4 = fmaf(hv, w2.x, a4);
                    a5 = fmaf(hv, w2.y, a5);
                }
            }
            // streamed rows 32q+12 .. 32q+31, 4-row lookahead
            {
                const float* hs = &hpl[32 * q + RREG + RLDS];
                float2 bufa[4], bufb[4], bufc[4];
#pragma unroll
                for (int d0 = 0; d0 < 4; ++d0) {
                    bufa[d0] = *reinterpret_cast<const float2*>(Rstr + (size_t)d0 * G3);
                    bufb[d0] = *reinterpret_cast<const float2*>(Rstr + (size_t)d0 * G3 + 2);
                    bufc[d0] = *reinterpret_cast<const float2*>(Rstr + (size_t)d0 * G3 + 4);
                }
#pragma unroll
                for (int m = 0; m < RSTR; ++m) {
                    const int s = m & 3;
                    const float hv = hs[m];
                    const float2 wa = bufa[s], wb = bufb[s], wc = bufc[s];
                    if (m + 4 < RSTR) {
                        bufa[s] = *reinterpret_cast<const float2*>(Rstr + (size_t)(m + 4) * G3);
                        bufb[s] = *reinterpret_cast<const float2*>(Rstr + (size_t)(m + 4) * G3 + 2);
                        bufc[s] = *reinterpret_cast<const float2*>(Rstr + (size_t)(m + 4) * G3 + 4);
                    }
                    a0 = fmaf(hv, wa.x, a0);
                    a1 = fmaf(hv, wa.y, a1);
                    a2 = fmaf(hv, wb.x, a2);
                    a3 = fmaf(hv, wb.y, a3);
                    a4 = fmaf(hv, wc.x, a4);
                    a5 = fmaf(hv, wc.y, a5);
                }
            }
            *reinterpret_cast<float2*>(&p2[q][c6])     = make_float2(a0, a1);
            *reinterpret_cast<float2*>(&p2[q][c6 + 2]) = make_float2(a2, a3);
            *reinterpret_cast<float2*>(&p2[q][c6 + 4]) = make_float2(a4, a5);
        }
        __syncthreads();                           // bar3

        // ---- S5: gates (t<256); cond-row prefetch (t in [256,384))
        if (t < 256) {
            float mz = b2z, mr_ = b2r, mc = b2h;
#pragma unroll
            for (int s = 0; s < 8; ++s) {
                mz  += p2[s][u];
                mr_ += p2[s][256 + u];
                mc  += p2[s][512 + u];
            }
            const float z    = 1.f / (1.f + expf(-(xz + mz)));
            const float r    = 1.f / (1.f + expf(-(xr + mr_)));
            const float cand = tanhf(xh + r * mc);
            outb[(size_t)i * H + u] = z * hp_reg + (1.f - z) * cand;
        } else if (t < 384 && i + 1 < T) {
            crow[(i + 1) & 1][t - 256] = condb[(size_t)(i + 1) * T + (t - 256)];
        }
    }
}

extern "C" void kernel_launch(void* const* d_in, const int* in_sizes, int n_in,
                              void* d_out, int out_size, void* d_ws, size_t ws_size,
                              hipStream_t stream) {
    const float* inputs     = (const float*)d_in[0];  // [B,T,D]
    const float* conditions = (const float*)d_in[1];  // [B,T,T]
    const float* kern       = (const float*)d_in[2];  // [D,3H]
    const float* rker       = (const float*)d_in[3];  // [H,3H]
    const float* bias       = (const float*)d_in[4];  // [2,3H]
    float* out = (float*)d_out;                       // [B,T,H] (also the history)
    float* MX  = (float*)d_ws;                        // [B*T, 3H]

    mx_gemm_kernel<<<(B * T) / 16, 256, 0, stream>>>(inputs, kern, bias, MX);
    rnn_kernel<<<B, NTH, 0, stream>>>(conditions, rker, bias, MX, out);
}

// Round 10
// 1735.215 us; speedup vs baseline: 1.3022x; 1.2998x over previous
//
#include <hip/hip_runtime.h>
#include <math.h>

#define B 64
#define T 128
#define D 256
#define H 256
#define G3 768
#define NTH 1024

// ---------------------------------------------------------------------------
// Kernel 1: MX[b,t,:] = inputs[b,t,:] @ kernel + bias[0]
// ---------------------------------------------------------------------------
__global__ __launch_bounds__(256) void mx_gemm_kernel(const float* __restrict__ x,
                                                      const float* __restrict__ K,
                                                      const float* __restrict__ bias,
                                                      float* __restrict__ MX) {
    __shared__ float xt[16][D];
    const int r0 = blockIdx.x * 16;
    const int tid = threadIdx.x;

    for (int idx = tid; idx < 16 * D; idx += 256) {
        xt[idx >> 8][idx & 255] = x[(size_t)(r0 + (idx >> 8)) * D + (idx & 255)];
    }
    __syncthreads();

    float acc0[16], acc1[16], acc2[16];
#pragma unroll
    for (int r = 0; r < 16; ++r) { acc0[r] = 0.f; acc1[r] = 0.f; acc2[r] = 0.f; }

    for (int d = 0; d < D; ++d) {
        float k0 = K[(size_t)d * G3 + tid];
        float k1 = K[(size_t)d * G3 + 256 + tid];
        float k2 = K[(size_t)d * G3 + 512 + tid];
#pragma unroll
        for (int r = 0; r < 16; ++r) {
            float xv = xt[r][d];
            acc0[r] += xv * k0;
            acc1[r] += xv * k1;
            acc2[r] += xv * k2;
        }
    }

    float b0 = bias[tid], b1 = bias[256 + tid], b2 = bias[512 + tid];
    for (int r = 0; r < 16; ++r) {
        size_t row = (size_t)(r0 + r) * G3;
        MX[row + tid]       = acc0[r] + b0;
        MX[row + 256 + tid] = acc1[r] + b1;
        MX[row + 512 + tid] = acc2[r] + b2;
    }
}

// ---------------------------------------------------------------------------
// Kernel 2: single-block-per-batch GRU recurrence, fp32 everywhere, hist in
// LDS. The R stream (768 KB/step from L2) IS the step time; everything else
// is scheduled under it:
//   - 8 float4 R-quads pre-issued during the PREVIOUS step's S5 (and before
//     the loop for i=1), re-issued inside S4 via a named-register depth-8
//     rotation (64 quads/thread total, fully unrolled, no runtime indexing).
//   - MX row i and cond row i+1 issued at S1-start, consumed at S5.
//   thread roles: all 1024 do S1 (8 strips x 2 units via float2);
//   t<768 stream (q=t/192 rows 64q..64q+63, cols 4c..4c+3, c=t%192);
//   t<256 reduce/gates; t>=960 cond prefetch.
// ---------------------------------------------------------------------------
__global__ __launch_bounds__(NTH) void rnn_kernel(const float* __restrict__ cond,
                                                  const float* __restrict__ R,
                                                  const float* __restrict__ bias,
                                                  const float* __restrict__ MX,
                                                  float* __restrict__ out) {
    const int b  = blockIdx.x;
    const int t  = threadIdx.x;
    const int u  = t & 255;         // S2/S5 unit
    const int v  = t & 127;         // S1 unit-pair index (units 2v, 2v+1)
    const int jq = t >> 7;          // 0..7  S1 j-strip (wave-uniform)
    const int q  = t / 192;         // 0..3 for t<768 (wave-uniform)
    const int c  = t % 192;         // col-quad -> cols 4c..4c+3

    __shared__ float hist2[T][H];                  // 131072 B
    __shared__ __align__(16) float hpl[H];         //   1024 B
    __shared__ float p1[8][H];                     //   8192 B
    __shared__ float p2[4][G3];                    //  12288 B
    __shared__ float crow[2][T];                   //   1024 B => 153600 B

    const float* condb = cond + (size_t)b * T * T;
    const float* mxb   = MX   + (size_t)b * T * G3;
    float*       outb  = out  + (size_t)b * T * H;
    const float4* Rq   = (const float4*)R;
    const int qi = (64 * q) * 192 + c;             // quad-index base (t<768)

    float4 r0q, r1q, r2q, r3q, r4q, r5q, r6q, r7q; // streaming rotation buffer
    float b2z = 0.f, b2r = 0.f, b2h = 0.f;
    float hp_reg = 0.f;

    // ---- init: bias, step-0 gates, cond row 1, first 8 R quads ----
    if (t < 256) {
        b2z = bias[G3 + u];
        b2r = bias[G3 + 256 + u];
        b2h = bias[G3 + 512 + u];
        const float xz = mxb[u], xr = mxb[256 + u], xh = mxb[512 + u];
        const float z    = 1.f / (1.f + expf(-(xz + b2z)));
        const float r    = 1.f / (1.f + expf(-(xr + b2r)));
        const float cand = tanhf(xh + r * b2h);
        const float hn   = (1.f - z) * cand;
        hist2[0][u] = hn;
        outb[u]     = hn;
    }
    if (t >= 960) {
        crow[1][t - 960]        = condb[T + (t - 960)];
        crow[1][64 + (t - 960)] = condb[T + 64 + (t - 960)];
    }
    if (t < 768) {
        r0q = Rq[qi];           r1q = Rq[qi + 192];
        r2q = Rq[qi + 2 * 192]; r3q = Rq[qi + 3 * 192];
        r4q = Rq[qi + 4 * 192]; r5q = Rq[qi + 5 * 192];
        r6q = Rq[qi + 6 * 192]; r7q = Rq[qi + 7 * 192];
    }
    __syncthreads();

    for (int i = 1; i < T; ++i) {
        // ---- S1: issue MX row i / cond row i+1; strip partials ----
        float mx0 = 0.f, mx1 = 0.f, mx2 = 0.f, cf0 = 0.f, cf1 = 0.f;
        if (t < 256) {
            const float* mrow = mxb + (size_t)i * G3;
            mx0 = mrow[u];
            mx1 = mrow[256 + u];
            mx2 = mrow[512 + u];
        }
        if (t >= 960 && i + 1 < T) {
            cf0 = condb[(size_t)(i + 1) * T + (t - 960)];
            cf1 = condb[(size_t)(i + 1) * T + 64 + (t - 960)];
        }
        {
            const float* cr = crow[i & 1];
            const int len = (i + 7) >> 3;
            const int j0 = jq * len;
            const int j1 = min(i, j0 + len);
            float ax = 0.f, ay = 0.f;
            for (int j = j0; j < j1; ++j) {
                const float cv = cr[j];
                const float2 hv = *(const float2*)&hist2[j][2 * v];
                ax = fmaf(cv, hv.x, ax);
                ay = fmaf(cv, hv.y, ay);
            }
            *(float2*)&p1[jq][2 * v] = make_float2(ax, ay);
        }
        __syncthreads();                           // bar1

        // ---- S2: hp reduce ----
        if (t < 256) {
            const float hp = ((p1[0][u] + p1[1][u]) + (p1[2][u] + p1[3][u]))
                           + ((p1[4][u] + p1[5][u]) + (p1[6][u] + p1[7][u]));
            hp_reg = hp;
            hpl[u] = hp;
        }
        __syncthreads();                           // bar2

        // ---- S4: 64-quad R stream, depth-8 rotation, 4-col accumulators ----
        if (t < 768) {
            float a0 = 0.f, a1 = 0.f, a2 = 0.f, a3 = 0.f;
            const float4* hp4 = (const float4*)&hpl[64 * q];
#define G4(BA, BB, BC, BD, m0, RE)                                              \
            { const float4 h4 = hp4[(m0) >> 2];                                 \
              a0 = fmaf(h4.x, BA.x, a0); a1 = fmaf(h4.x, BA.y, a1);             \
              a2 = fmaf(h4.x, BA.z, a2); a3 = fmaf(h4.x, BA.w, a3);             \
              if (RE) BA = Rq[qi + ((m0) + 8) * 192];                           \
              a0 = fmaf(h4.y, BB.x, a0); a1 = fmaf(h4.y, BB.y, a1);             \
              a2 = fmaf(h4.y, BB.z, a2); a3 = fmaf(h4.y, BB.w, a3);             \
              if (RE) BB = Rq[qi + ((m0) + 9) * 192];                           \
              a0 = fmaf(h4.z, BC.x, a0); a1 = fmaf(h4.z, BC.y, a1);             \
              a2 = fmaf(h4.z, BC.z, a2); a3 = fmaf(h4.z, BC.w, a3);             \
              if (RE) BC = Rq[qi + ((m0) + 10) * 192];                          \
              a0 = fmaf(h4.w, BD.x, a0); a1 = fmaf(h4.w, BD.y, a1);             \
              a2 = fmaf(h4.w, BD.z, a2); a3 = fmaf(h4.w, BD.w, a3);             \
              if (RE) BD = Rq[qi + ((m0) + 11) * 192]; }
            G4(r0q, r1q, r2q, r3q,  0, 1) G4(r4q, r5q, r6q, r7q,  4, 1)
            G4(r0q, r1q, r2q, r3q,  8, 1) G4(r4q, r5q, r6q, r7q, 12, 1)
            G4(r0q, r1q, r2q, r3q, 16, 1) G4(r4q, r5q, r6q, r7q, 20, 1)
            G4(r0q, r1q, r2q, r3q, 24, 1) G4(r4q, r5q, r6q, r7q, 28, 1)
            G4(r0q, r1q, r2q, r3q, 32, 1) G4(r4q, r5q, r6q, r7q, 36, 1)
            G4(r0q, r1q, r2q, r3q, 40, 1) G4(r4q, r5q, r6q, r7q, 44, 1)
            G4(r0q, r1q, r2q, r3q, 48, 1) G4(r4q, r5q, r6q, r7q, 52, 1)
            G4(r0q, r1q, r2q, r3q, 56, 0) G4(r4q, r5q, r6q, r7q, 60, 0)
#undef G4
            *(float4*)&p2[q][4 * c] = make_float4(a0, a1, a2, a3);
        }
        __syncthreads();                           // bar3

        // ---- S5: next-step R pre-issue; gates; crow commit ----
        if (t < 768 && i + 1 < T) {
            r0q = Rq[qi];           r1q = Rq[qi + 192];
            r2q = Rq[qi + 2 * 192]; r3q = Rq[qi + 3 * 192];
            r4q = Rq[qi + 4 * 192]; r5q = Rq[qi + 5 * 192];
            r6q = Rq[qi + 6 * 192]; r7q = Rq[qi + 7 * 192];
        }
        if (t < 256) {
            const float mz = b2z + ((p2[0][u] + p2[1][u]) + (p2[2][u] + p2[3][u]));
            const float mr = b2r + ((p2[0][256 + u] + p2[1][256 + u])
                                  + (p2[2][256 + u] + p2[3][256 + u]));
            const float mc = b2h + ((p2[0][512 + u] + p2[1][512 + u])
                                  + (p2[2][512 + u] + p2[3][512 + u]));
            const float z    = 1.f / (1.f + expf(-(mx0 + mz)));
            const float r    = 1.f / (1.f + expf(-(mx1 + mr)));
            const float cand = tanhf(mx2 + r * mc);
            const float hn   = z * hp_reg + (1.f - z) * cand;
            hist2[i][u] = hn;
            outb[(size_t)i * H + u] = hn;
        } else if (t >= 960 && i + 1 < T) {
            crow[(i + 1) & 1][t - 960]        = cf0;
            crow[(i + 1) & 1][64 + (t - 960)] = cf1;
        }
        __syncthreads();                           // bar0 (next iter)
    }
}

extern "C" void kernel_launch(void* const* d_in, const int* in_sizes, int n_in,
                              void* d_out, int out_size, void* d_ws, size_t ws_size,
                              hipStream_t stream) {
    const float* inputs     = (const float*)d_in[0];  // [B,T,D]
    const float* conditions = (const float*)d_in[1];  // [B,T,T]
    const float* kern       = (const float*)d_in[2];  // [D,3H]
    const float* rker       = (const float*)d_in[3];  // [H,3H]
    const float* bias       = (const float*)d_in[4];  // [2,3H]
    float* out = (float*)d_out;                       // [B,T,H]
    float* MX  = (float*)d_ws;                        // [B*T, 3H]

    mx_gemm_kernel<<<(B * T) / 16, 256, 0, stream>>>(inputs, kern, bias, MX);
    rnn_kernel<<<B, NTH, 0, stream>>>(conditions, rker, bias, MX, out);
}

// Round 11
// 1443.404 us; speedup vs baseline: 1.5655x; 1.2022x over previous
//
#include <hip/hip_runtime.h>
#include <math.h>

#define B 64
#define T 128
#define D 256
#define H 256
#define G3 768
#define NTH 1024

// ---------------------------------------------------------------------------
// Kernel 1: MX[b,t,:] = inputs[b,t,:] @ kernel + bias[0]
// ---------------------------------------------------------------------------
__global__ __launch_bounds__(256) void mx_gemm_kernel(const float* __restrict__ x,
                                                      const float* __restrict__ K,
                                                      const float* __restrict__ bias,
                                                      float* __restrict__ MX) {
    __shared__ float xt[16][D];
    const int r0 = blockIdx.x * 16;
    const int tid = threadIdx.x;

    for (int idx = tid; idx < 16 * D; idx += 256) {
        xt[idx >> 8][idx & 255] = x[(size_t)(r0 + (idx >> 8)) * D + (idx & 255)];
    }
    __syncthreads();

    float acc0[16], acc1[16], acc2[16];
#pragma unroll
    for (int r = 0; r < 16; ++r) { acc0[r] = 0.f; acc1[r] = 0.f; acc2[r] = 0.f; }

    for (int d = 0; d < D; ++d) {
        float k0 = K[(size_t)d * G3 + tid];
        float k1 = K[(size_t)d * G3 + 256 + tid];
        float k2 = K[(size_t)d * G3 + 512 + tid];
#pragma unroll
        for (int r = 0; r < 16; ++r) {
            float xv = xt[r][d];
            acc0[r] += xv * k0;
            acc1[r] += xv * k1;
            acc2[r] += xv * k2;
        }
    }

    float b0 = bias[tid], b1 = bias[256 + tid], b2 = bias[512 + tid];
    for (int r = 0; r < 16; ++r) {
        size_t row = (size_t)(r0 + r) * G3;
        MX[row + tid]       = acc0[r] + b0;
        MX[row + 256 + tid] = acc1[r] + b1;
        MX[row + 512 + tid] = acc2[r] + b2;
    }
}

// ---------------------------------------------------------------------------
// Kernel 2: single-block-per-batch GRU, fp32, hist in LDS, php-fusion.
//   Per step i (2 barriers):
//   Phase A: waves 0-11 (t<768): R stream (straight unrolled loop, compiler-
//            hoisted loads; q=t/192 owns rows 64q..64q+63 staggered by rot,
//            cols 4c..4c+3) -> p2;  t<256 also issue MX row i loads.
//            waves 12-15 (t>=768): php[u] = sum_{j<i} c[i+1,j]*h_j[u]
//            (hidden under the stream) + prefetch cond row i+2.
//   Phase B: t<256: mh reduce + gates -> h_i; hpl_{i+1} = php[u]+c[i+1,i]*h_i.
// ---------------------------------------------------------------------------
__global__ __launch_bounds__(NTH) void rnn_kernel(const float* __restrict__ cond,
                                                  const float* __restrict__ R,
                                                  const float* __restrict__ bias,
                                                  const float* __restrict__ MX,
                                                  float* __restrict__ out) {
    const int b  = blockIdx.x;
    const int t  = threadIdx.x;
    const int u  = t & 255;
    const int q  = t / 192;        // 0..3 for t<768 (wave-uniform)
    const int c  = t % 192;        // col-quad -> cols 4c..4c+3
    const int pu = t - 768;        // php unit for t>=768

    __shared__ float hist2[T][H];                  // 131072 B
    __shared__ float p2[4][G3];                    //  12288 B
    __shared__ __align__(16) float hpl[H];         //   1024 B
    __shared__ float phpl[H];                      //   1024 B
    __shared__ float crow[2][T];                   //   1024 B => 146432 B

    const float* condb = cond + (size_t)b * T * T;
    const float* mxb   = MX   + (size_t)b * T * G3;
    float*       outb  = out  + (size_t)b * T * H;
    const float4* Rq   = (const float4*)R;
    const int rot = ((b >> 3) & 7) << 3;  // same-XCD blocks start at different rows

    float b2z = 0.f, b2r = 0.f, b2h = 0.f, hp_reg = 0.f;

    // ---- prologue: step-0 gates, hpl_1, cond row 2 ----
    if (t < 256) {
        b2z = bias[G3 + u];
        b2r = bias[G3 + 256 + u];
        b2h = bias[G3 + 512 + u];
        const float xz = mxb[u], xr = mxb[256 + u], xh = mxb[512 + u];
        const float z    = 1.f / (1.f + expf(-(xz + b2z)));
        const float r    = 1.f / (1.f + expf(-(xr + b2r)));
        const float cand = tanhf(xh + r * b2h);
        const float hn   = (1.f - z) * cand;
        hist2[0][u] = hn;
        outb[u]     = hn;
        hp_reg = condb[T] * hn;           // c[1,0] * h0
        hpl[u] = hp_reg;
    }
    if (t >= 256 && t < 384) crow[0][t - 256] = condb[2 * T + (t - 256)];  // row 2
    __syncthreads();

    for (int i = 1; i < T; ++i) {
        // ---------------- Phase A ----------------
        float mx0 = 0.f, mx1 = 0.f, mx2 = 0.f;
        if (t < 768) {
            if (t < 256) {                 // issue MX row i early (consumed phase B)
                const float* mrow = mxb + (size_t)i * G3;
                mx0 = mrow[u];
                mx1 = mrow[256 + u];
                mx2 = mrow[512 + u];
            }
            // R stream: 64 rows x 4 cols, straight loop (compiler hoists loads)
            float a0 = 0.f, a1 = 0.f, a2 = 0.f, a3 = 0.f;
            const int rowbase = 64 * q;
            const float4* Rc = Rq + c;
#pragma unroll
            for (int g = 0; g < 16; ++g) {
                const int rr = (4 * g + rot) & 63;
                const float4 h4 = *(const float4*)&hpl[rowbase + rr];
                const float4 w0 = Rc[(size_t)(rowbase + rr)     * 192];
                const float4 w1 = Rc[(size_t)(rowbase + rr + 1) * 192];
                const float4 w2 = Rc[(size_t)(rowbase + rr + 2) * 192];
                const float4 w3 = Rc[(size_t)(rowbase + rr + 3) * 192];
                a0 = fmaf(h4.x, w0.x, a0); a1 = fmaf(h4.x, w0.y, a1);
                a2 = fmaf(h4.x, w0.z, a2); a3 = fmaf(h4.x, w0.w, a3);
                a0 = fmaf(h4.y, w1.x, a0); a1 = fmaf(h4.y, w1.y, a1);
                a2 = fmaf(h4.y, w1.z, a2); a3 = fmaf(h4.y, w1.w, a3);
                a0 = fmaf(h4.z, w2.x, a0); a1 = fmaf(h4.z, w2.y, a1);
                a2 = fmaf(h4.z, w2.z, a2); a3 = fmaf(h4.z, w2.w, a3);
                a0 = fmaf(h4.w, w3.x, a0); a1 = fmaf(h4.w, w3.y, a1);
                a2 = fmaf(h4.w, w3.z, a2); a3 = fmaf(h4.w, w3.w, a3);
            }
            *(float4*)&p2[q][4 * c] = make_float4(a0, a1, a2, a3);
        } else {
            // php waves: next-step history sum + cond row i+2 prefetch
            float cf = 0.f;
            if (pu < 128 && i + 2 < T) cf = condb[(size_t)(i + 2) * T + pu];
            if (i + 1 < T) {
                const float* cr = crow[(i + 1) & 1];
                float a = 0.f;
                for (int j = 0; j < i; ++j) a = fmaf(cr[j], hist2[j][pu], a);
                phpl[pu] = a;
            }
            if (pu < 128 && i + 2 < T) crow[i & 1][pu] = cf;
        }
        __syncthreads();                           // bar A->B

        // ---------------- Phase B ----------------
        if (t < 256) {
            const float mz = b2z + ((p2[0][u] + p2[1][u]) + (p2[2][u] + p2[3][u]));
            const float mr_ = b2r + ((p2[0][256 + u] + p2[1][256 + u])
                                   + (p2[2][256 + u] + p2[3][256 + u]));
            const float mc = b2h + ((p2[0][512 + u] + p2[1][512 + u])
                                  + (p2[2][512 + u] + p2[3][512 + u]));
            const float z    = 1.f / (1.f + expf(-(mx0 + mz)));
            const float r    = 1.f / (1.f + expf(-(mx1 + mr_)));
            const float cand = tanhf(mx2 + r * mc);
            const float hn   = z * hp_reg + (1.f - z) * cand;
            hist2[i][u] = hn;
            outb[(size_t)i * H + u] = hn;
            if (i + 1 < T) {
                hp_reg = phpl[u] + crow[(i + 1) & 1][i] * hn;
                hpl[u] = hp_reg;
            }
        }
        __syncthreads();                           // bar B->A (next step)
    }
}

extern "C" void kernel_launch(void* const* d_in, const int* in_sizes, int n_in,
                              void* d_out, int out_size, void* d_ws, size_t ws_size,
                              hipStream_t stream) {
    const float* inputs     = (const float*)d_in[0];  // [B,T,D]
    const float* conditions = (const float*)d_in[1];  // [B,T,T]
    const float* kern       = (const float*)d_in[2];  // [D,3H]
    const float* rker       = (const float*)d_in[3];  // [H,3H]
    const float* bias       = (const float*)d_in[4];  // [2,3H]
    float* out = (float*)d_out;                       // [B,T,H]
    float* MX  = (float*)d_ws;                        // [B*T, 3H]

    mx_gemm_kernel<<<(B * T) / 16, 256, 0, stream>>>(inputs, kern, bias, MX);
    rnn_kernel<<<B, NTH, 0, stream>>>(conditions, rker, bias, MX, out);
}